// Round 1
// baseline (913.262 us; speedup 1.0000x reference)
//
#include <hip/hip_runtime.h>
#include <stdint.h>

#define T_TOK 8192
#define H_DIM 2048
#define F_DIM 1408
#define E_NUM 8
#define GU_DIM 2816   /* 2F */
#define NSLOT 16384   /* T * top_k */

typedef short bf16x8 __attribute__((ext_vector_type(8)));
typedef float f32x4 __attribute__((ext_vector_type(4)));

__device__ __forceinline__ unsigned short f2bf(float f) {
  union { float f; unsigned u; } v; v.f = f;
  unsigned r = v.u + 0x7fffu + ((v.u >> 16) & 1u);
  return (unsigned short)(r >> 16);
}
__device__ __forceinline__ float bf2f(unsigned short h) {
  union { unsigned u; float f; } v; v.u = ((unsigned)h) << 16;
  return v.f;
}

__device__ __forceinline__ void gload16(const unsigned short* g, unsigned short* l) {
  __builtin_amdgcn_global_load_lds(
      (const __attribute__((address_space(1))) unsigned int*)g,
      (__attribute__((address_space(3))) unsigned int*)l, 16, 0, 0);
}

/* ---------------- cast fp32 -> bf16, vectorized x4 ---------------- */
__global__ void cast_kernel(const float* __restrict__ in,
                            unsigned short* __restrict__ out, long n4) {
  long i = (long)blockIdx.x * blockDim.x + threadIdx.x;
  long stride = (long)gridDim.x * blockDim.x;
  for (; i < n4; i += stride) {
    float4 f = ((const float4*)in)[i];
    ushort4 o;
    o.x = f2bf(f.x); o.y = f2bf(f.y); o.z = f2bf(f.z); o.w = f2bf(f.w);
    ((ushort4*)out)[i] = o;
  }
}

/* cast w1 with gate/up row interleave:
 * dst row n (within expert): group=n>>5, within=n&31, f=group*16+(within&15)
 * src row = (within<16) ? f : F_DIM+f.
 * => GEMM1 columns n and n+16 (within each 32-group) are gate_f and up_f. */
__global__ void cast_w1_kernel(const float* __restrict__ w1,
                               unsigned short* __restrict__ W1bf) {
  const long n4tot = (long)E_NUM * GU_DIM * (H_DIM / 4);
  long i = (long)blockIdx.x * blockDim.x + threadIdx.x;
  long stride = (long)gridDim.x * blockDim.x;
  for (; i < n4tot; i += stride) {
    int h4 = (int)(i & (H_DIM / 4 - 1));      // 512 per row, pow2
    long rn = i >> 9;
    int n = (int)(rn % GU_DIM);
    int e = (int)(rn / GU_DIM);
    int group = n >> 5, within = n & 31;
    int f = group * 16 + (within & 15);
    int src = (within < 16) ? f : (F_DIM + f);
    float4 v = ((const float4*)w1)[((long)e * GU_DIM + src) * (H_DIM / 4) + h4];
    ushort4 o;
    o.x = f2bf(v.x); o.y = f2bf(v.y); o.z = f2bf(v.z); o.w = f2bf(v.w);
    ((ushort4*)W1bf)[i] = o;
  }
}

/* ---------------- router: softmax top-2 + counts ---------------- */
__global__ void router_kernel(const float* __restrict__ logits,
                              int* __restrict__ counts,
                              int* __restrict__ tok_e, float* __restrict__ tok_w) {
  int t = blockIdx.x * blockDim.x + threadIdx.x;
  if (t >= T_TOK) return;
  float l[E_NUM];
  float4 a = ((const float4*)logits)[(size_t)t * 2];
  float4 b = ((const float4*)logits)[(size_t)t * 2 + 1];
  l[0]=a.x; l[1]=a.y; l[2]=a.z; l[3]=a.w;
  l[4]=b.x; l[5]=b.y; l[6]=b.z; l[7]=b.w;
  int i0 = 0; float m0v = l[0];
  #pragma unroll
  for (int e = 1; e < E_NUM; ++e) if (l[e] > m0v) { m0v = l[e]; i0 = e; }
  int i1 = -1; float m1v = -3.0e38f;
  #pragma unroll
  for (int e = 0; e < E_NUM; ++e) if (e != i0 && l[e] > m1v) { m1v = l[e]; i1 = e; }
  float e1 = __expf(m1v - m0v);
  float inv = 1.0f / (1.0f + e1);
  tok_e[2*t]   = i0; tok_w[2*t]   = inv;
  tok_e[2*t+1] = i1; tok_w[2*t+1] = e1 * inv;
  atomicAdd(&counts[i0], 1);
  atomicAdd(&counts[i1], 1);
}

__global__ void scan_kernel(const int* __restrict__ counts,
                            int* __restrict__ offsets, int* __restrict__ cursors) {
  if (threadIdx.x == 0 && blockIdx.x == 0) {
    int o = 0;
    for (int e = 0; e < E_NUM; ++e) { offsets[e] = o; cursors[e] = o; o += counts[e]; }
  }
}

__global__ void scatter_kernel(const int* __restrict__ tok_e, const float* __restrict__ tok_w,
                               int* __restrict__ cursors,
                               int* __restrict__ token_ids, float* __restrict__ slot_w,
                               int* __restrict__ slot_of) {
  int t = blockIdx.x * blockDim.x + threadIdx.x;
  if (t >= T_TOK) return;
  #pragma unroll
  for (int j = 0; j < 2; ++j) {
    int e = tok_e[2*t+j];
    int slot = atomicAdd(&cursors[e], 1);
    token_ids[slot] = t;
    slot_w[slot] = tok_w[2*t+j];
    slot_of[2*t+j] = slot;
  }
}

/* ---------------- 256x256 8-phase bf16 MFMA GEMM, C = A * B^T ----------------
 * BM=BN=256, BK=64, 512 threads (8 waves, 2M x 4N), 16x16x32 mfma.
 * LDS 128 KiB: A/B each 2 dbuf x 2 half(128x64) x 16 KiB. Chunk-XOR swizzle:
 * LDS slot (r, c16) holds global chunk c ^ (r&7) -> ds_read_b128 conflict-free.
 *
 * Per K-tile, the 4 phases are the 4 block-level 128x128 C-quadrants in order
 * Q(qm,qn) = (0,0),(0,1),(1,0),(1,1) so each phase reads exactly one A-half
 * (qm) and one B-half (qn). Half-tile stage schedule (1 half / phase):
 *   P1: A1(t+1)   P2: B1(t+1)   P3: A0(t+2)   P4: B0(t+2)
 * Write-after-read: each region's last ds_read is >=1 phase-barrier earlier.
 * Landing: at each K-tile boundary exactly 2 halves (4 loads) are in flight
 * -> s_waitcnt vmcnt(4) at the boundary only (vmcnt(0) in the last 2 tiles).
 * Raw s_barrier (no implicit vmcnt drain), lgkmcnt(0)+sched_barrier before
 * each 16-MFMA cluster, setprio(1) around it (T3+T4+T5).
 */
#define BARRIER() __builtin_amdgcn_s_barrier()
#define WAIT_LGKM0() do { \
    asm volatile("s_waitcnt lgkmcnt(0)" ::: "memory"); \
    __builtin_amdgcn_sched_barrier(0); \
  } while (0)
#define WAIT_VM4() asm volatile("s_waitcnt vmcnt(4)" ::: "memory")
#define WAIT_VM0() asm volatile("s_waitcnt vmcnt(0)" ::: "memory")

#define STAGE(BASE, P, KOFF) do { \
    gload16((P)[0] + (KOFF), &lds[(BASE) + (w << 9)]); \
    gload16((P)[1] + (KOFF), &lds[(BASE) + 4096 + (w << 9)]); \
  } while (0)

#define LOADA(BASE) do { \
    _Pragma("unroll") \
    for (int tm_ = 0; tm_ < 4; ++tm_) { \
      af[tm_][0] = *(const bf16x8*)&lds[(BASE) + aoff[tm_] + koff0]; \
      af[tm_][1] = *(const bf16x8*)&lds[(BASE) + aoff[tm_] + koff1]; \
    } \
  } while (0)

#define LOADB(BASE) do { \
    _Pragma("unroll") \
    for (int tn_ = 0; tn_ < 2; ++tn_) { \
      bfr[tn_][0] = *(const bf16x8*)&lds[(BASE) + boff[tn_] + koff0]; \
      bfr[tn_][1] = *(const bf16x8*)&lds[(BASE) + boff[tn_] + koff1]; \
    } \
  } while (0)

#define MMAQ(Q) do { \
    _Pragma("unroll") \
    for (int tm_ = 0; tm_ < 4; ++tm_) { \
      _Pragma("unroll") \
      for (int tn_ = 0; tn_ < 2; ++tn_) { \
        acc[Q][tm_][tn_] = __builtin_amdgcn_mfma_f32_16x16x32_bf16( \
            af[tm_][0], bfr[tn_][0], acc[Q][tm_][tn_], 0, 0, 0); \
        acc[Q][tm_][tn_] = __builtin_amdgcn_mfma_f32_16x16x32_bf16( \
            af[tm_][1], bfr[tn_][1], acc[Q][tm_][tn_], 0, 0, 0); \
      } \
    } \
  } while (0)

template <int K, bool GATHER, int EPI>
__global__ __launch_bounds__(512, 2)
void gemm256_kernel(const unsigned short* __restrict__ A,
                    const unsigned short* __restrict__ B,
                    const int* __restrict__ counts, const int* __restrict__ offsets,
                    const int* __restrict__ token_ids, const float* __restrict__ slot_w,
                    unsigned short* __restrict__ OutB, long bstride_e) {
  constexpr int NT = K / 64;
  const int e = blockIdx.z;
  const int count = counts[e];
  const int m0 = blockIdx.y * 256;
  if (m0 >= count) return;
  const int n0 = blockIdx.x * 256;
  const int off = offsets[e];
  const unsigned short* Bexp = B + (size_t)e * bstride_e;

  /* A: [0,32768) shorts, B: [32768,65536). region(buf,half) = 8192 shorts. */
  __shared__ __align__(16) unsigned short lds[65536];

  const int t = threadIdx.x;
  const int w = t >> 6, lane = t & 63;
  const int wm = w >> 2, wn = w & 3;
  const int quad = lane >> 4, col = lane & 15;
  const int sw = col & 7;

  /* staging pointers: pa[half][sweep] covers row half*128 + sweep*64 + t/8,
   * global chunk (t&7)^((t>>3)&7) (source pre-swizzle for linear LDS dest). */
  const int colb = (((t & 7) ^ ((t >> 3) & 7)) * 8);
  const unsigned short* pa[2][2];
  const unsigned short* pb[2][2];
  #pragma unroll
  for (int h = 0; h < 2; ++h)
    #pragma unroll
    for (int s = 0; s < 2; ++s) {
      int r = h * 128 + s * 64 + (t >> 3);
      int mr = m0 + r;
      if (GATHER) {
        int tok = (mr < count) ? token_ids[off + mr] : 0;
        pa[h][s] = A + (size_t)tok * K + colb;
      } else {
        int row = (mr < count) ? (off + mr) : 0;
        pa[h][s] = A + (size_t)row * K + colb;
      }
      pb[h][s] = Bexp + (size_t)(n0 + r) * K + colb;
    }

  /* fragment LDS offsets (shorts): row stride 64, chunk-XOR on k-chunk */
  int aoff[4], boff[2];
  #pragma unroll
  for (int tm = 0; tm < 4; ++tm) aoff[tm] = (wm * 64 + tm * 16 + col) * 64;
  #pragma unroll
  for (int tn = 0; tn < 2; ++tn) boff[tn] = (wn * 32 + tn * 16 + col) * 64;
  const int koff0 = ((0 * 4 + quad) ^ sw) * 8;
  const int koff1 = ((1 * 4 + quad) ^ sw) * 8;

  const f32x4 zero = {0.f, 0.f, 0.f, 0.f};
  f32x4 acc[4][4][2];
  #pragma unroll
  for (int q = 0; q < 4; ++q)
    #pragma unroll
    for (int tm = 0; tm < 4; ++tm)
      #pragma unroll
      for (int tn = 0; tn < 2; ++tn) acc[q][tm][tn] = zero;

  bf16x8 af[4][2], bfr[2][2];

  /* -------- prologue: tile0 fully + tile1 A0,B0; leave 2 halves in flight */
  STAGE(0,             pa[0], 0);    // A0(0) -> buf0
  STAGE(32768,         pb[0], 0);    // B0(0)
  STAGE(8192,          pa[1], 0);    // A1(0)
  STAGE(32768 + 8192,  pb[1], 0);    // B1(0)
  STAGE(16384,         pa[0], 64);   // A0(1) -> buf1
  STAGE(32768 + 16384, pb[0], 64);   // B0(1)
  WAIT_VM4();
  BARRIER();

  for (int u = 0; u < NT; ++u) {
    const int b = u & 1, nb = b ^ 1;
    const int bA0 = (b * 2 + 0) * 8192, bA1 = (b * 2 + 1) * 8192;
    const int bB0 = 32768 + bA0,        bB1 = 32768 + bA1;
    const int nA1 = (nb * 2 + 1) * 8192, nB1 = 32768 + nA1;
    const int k1 = (u + 1) * 64, k2 = (u + 2) * 64;

    /* ---- phase 1: Q(0,0); stage A1(u+1) ---- */
    LOADA(bA0); LOADB(bB0);
    if (u + 1 < NT) STAGE(nA1, pa[1], k1);
    BARRIER(); WAIT_LGKM0();
    __builtin_amdgcn_s_setprio(1); MMAQ(0); __builtin_amdgcn_s_setprio(0);
    BARRIER();

    /* ---- phase 2: Q(0,1); reuse af; stage B1(u+1) ---- */
    LOADB(bB1);
    if (u + 1 < NT) STAGE(nB1, pb[1], k1);
    BARRIER(); WAIT_LGKM0();
    __builtin_amdgcn_s_setprio(1); MMAQ(1); __builtin_amdgcn_s_setprio(0);
    BARRIER();

    /* ---- phase 3: Q(1,0); stage A0(u+2) ---- */
    LOADA(bA1); LOADB(bB0);
    if (u + 2 < NT) STAGE(bA0, pa[0], k2);
    BARRIER(); WAIT_LGKM0();
    __builtin_amdgcn_s_setprio(1); MMAQ(2); __builtin_amdgcn_s_setprio(0);
    BARRIER();

    /* ---- phase 4: Q(1,1); reuse af; stage B0(u+2); boundary fence ---- */
    LOADB(bB1);
    if (u + 2 < NT) STAGE(bB0, pb[0], k2);
    BARRIER(); WAIT_LGKM0();
    __builtin_amdgcn_s_setprio(1); MMAQ(3); __builtin_amdgcn_s_setprio(0);
    if (u + 2 < NT) { WAIT_VM4(); } else { WAIT_VM0(); }
    BARRIER();
  }

  /* -------- epilogue. C/D: col=lane&15 (N), row=quad*4+reg (M). -------- */
  if (EPI == 0) {
    /* gate/up interleave: within each 32-col group, tn=0 is gate, tn=1 is up;
     * f = (n0 + qn*128 + wn*32)/2 + col. */
    #pragma unroll
    for (int q = 0; q < 4; ++q) {
      const int qm = q >> 1, qn = q & 1;
      const int fb = (n0 >> 1) + qn * 64 + wn * 16 + col;
      #pragma unroll
      for (int tm = 0; tm < 4; ++tm)
        #pragma unroll
        for (int reg = 0; reg < 4; ++reg) {
          int m_l = qm * 128 + wm * 64 + tm * 16 + quad * 4 + reg;
          if (m0 + m_l < count) {
            float g = acc[q][tm][0][reg], uu = acc[q][tm][1][reg];
            OutB[(size_t)(off + m0 + m_l) * F_DIM + fb] =
                f2bf(g / (1.f + __expf(-g)) * uu);
          }
        }
    }
  } else {
    #pragma unroll
    for (int q = 0; q < 4; ++q) {
      const int qm = q >> 1, qn = q & 1;
      #pragma unroll
      for (int tm = 0; tm < 4; ++tm)
        #pragma unroll
        for (int reg = 0; reg < 4; ++reg) {
          int m_l = qm * 128 + wm * 64 + tm * 16 + quad * 4 + reg;
          if (m0 + m_l < count) {
            int slot = off + m0 + m_l;
            float wv = slot_w[slot];
            unsigned short* yrow = OutB + (size_t)slot * H_DIM + n0 + qn * 128 + wn * 32;
            yrow[col]      = f2bf(wv * acc[q][tm][0][reg]);
            yrow[16 + col] = f2bf(wv * acc[q][tm][1][reg]);
          }
        }
    }
  }
}

/* ---------------- out[t] = Y[s0(t)] + Y[s1(t)] ---------------- */
__global__ void combine_kernel(const unsigned short* __restrict__ Y,
                               const int* __restrict__ slot_of,
                               float* __restrict__ out) {
  const long n4 = (long)T_TOK * (H_DIM / 4);
  long i = (long)blockIdx.x * blockDim.x + threadIdx.x;
  long stride = (long)gridDim.x * blockDim.x;
  for (; i < n4; i += stride) {
    int h4 = (int)(i & (H_DIM / 4 - 1));
    int t = (int)(i >> 9);
    int s0 = slot_of[2 * t], s1 = slot_of[2 * t + 1];
    ushort4 a = ((const ushort4*)(Y + (size_t)s0 * H_DIM))[h4];
    ushort4 b = ((const ushort4*)(Y + (size_t)s1 * H_DIM))[h4];
    float4 o;
    o.x = bf2f(a.x) + bf2f(b.x);
    o.y = bf2f(a.y) + bf2f(b.y);
    o.z = bf2f(a.z) + bf2f(b.z);
    o.w = bf2f(a.w) + bf2f(b.w);
    ((float4*)out)[i] = o;
  }
}

extern "C" void kernel_launch(void* const* d_in, const int* in_sizes, int n_in,
                              void* d_out, int out_size, void* d_ws, size_t ws_size,
                              hipStream_t stream) {
  const float* hidden = (const float*)d_in[0];
  const float* rlog   = (const float*)d_in[1];
  const float* w1     = (const float*)d_in[2];
  const float* w2     = (const float*)d_in[3];
  float* out = (float*)d_out;
  char* ws = (char*)d_ws;

  size_t o = 0;
  auto take = [&](size_t bytes) { size_t r = o; o += (bytes + 255) & ~(size_t)255; return r; };
  unsigned short* Xbf  = (unsigned short*)(ws + take((size_t)T_TOK * H_DIM * 2));
  unsigned short* W1bf = (unsigned short*)(ws + take((size_t)E_NUM * GU_DIM * H_DIM * 2));
  unsigned short* W2bf = (unsigned short*)(ws + take((size_t)E_NUM * H_DIM * F_DIM * 2));
  unsigned short* Hb   = (unsigned short*)(ws + take((size_t)NSLOT * F_DIM * 2));
  unsigned short* Y    = (unsigned short*)(ws + take((size_t)NSLOT * H_DIM * 2));
  size_t ctrl_off = take(256 * 3);           // counts / offsets / cursors
  int* counts  = (int*)(ws + ctrl_off);
  int* offsets = (int*)(ws + ctrl_off + 256);
  int* cursors = (int*)(ws + ctrl_off + 512);
  int*   tok_e     = (int*)(ws + take((size_t)T_TOK * 2 * 4));
  float* tok_w     = (float*)(ws + take((size_t)T_TOK * 2 * 4));
  int*   token_ids = (int*)(ws + take((size_t)NSLOT * 4));
  float* slot_w    = (float*)(ws + take((size_t)NSLOT * 4));
  int*   slot_of   = (int*)(ws + take((size_t)NSLOT * 4));

  hipMemsetAsync(ws + ctrl_off, 0, 256 * 3, stream);

  cast_kernel<<<2048, 256, 0, stream>>>(hidden, Xbf, (long)T_TOK * H_DIM / 4);
  cast_w1_kernel<<<4096, 256, 0, stream>>>(w1, W1bf);
  cast_kernel<<<4096, 256, 0, stream>>>(w2, W2bf, (long)E_NUM * H_DIM * F_DIM / 4);

  router_kernel<<<T_TOK / 256, 256, 0, stream>>>(rlog, counts, tok_e, tok_w);
  scan_kernel<<<1, 64, 0, stream>>>(counts, offsets, cursors);
  scatter_kernel<<<T_TOK / 256, 256, 0, stream>>>(tok_e, tok_w, cursors,
                                                  token_ids, slot_w, slot_of);

  /* max per-expert count = T_TOK (top-2 experts are distinct) -> y = 8192/256 */
  dim3 g1(GU_DIM / 256, T_TOK / 256, E_NUM);
  gemm256_kernel<H_DIM, true, 0><<<g1, 512, 0, stream>>>(
      Xbf, W1bf, counts, offsets, token_ids, slot_w, Hb,
      (long)GU_DIM * H_DIM);

  dim3 g2(H_DIM / 256, T_TOK / 256, E_NUM);
  gemm256_kernel<F_DIM, false, 1><<<g2, 512, 0, stream>>>(
      Hb, W2bf, counts, offsets, token_ids, slot_w, Y,
      (long)H_DIM * F_DIM);

  combine_kernel<<<4096, 256, 0, stream>>>(Y, slot_of, out);
}